// Round 1
// baseline (134.623 us; speedup 1.0000x reference)
//
#include <hip/hip_runtime.h>

// Problem constants (B=1 fixed by reference)
#define HW_TOTAL (480 * 640)        // 307200 pixels
#define NC 12                        // output channels (C-1)
#define C_IN 13
#define VOX_TOTAL_C (240 * 144 * 240) // 8,294,400 voxels

__global__ void reproj_scatter_kernel(const float* __restrict__ x,
                                      const int* __restrict__ map,
                                      float* __restrict__ out) {
    int p = blockIdx.x * blockDim.x + threadIdx.x;
    if (p >= HW_TOTAL) return;
    int v = map[p];
    if (v <= 0) return;  // invalid pixel (reference drops idx==0 via VOX_TOTAL sentinel)
    // x layout: (C_IN, HW); we take channels 1..12.
    // out layout: (NC, VOX_TOTAL).
#pragma unroll
    for (int c = 0; c < NC; ++c) {
        out[(size_t)c * VOX_TOTAL_C + (size_t)v] =
            x[(size_t)(c + 1) * HW_TOTAL + (size_t)p];
    }
}

extern "C" void kernel_launch(void* const* d_in, const int* in_sizes, int n_in,
                              void* d_out, int out_size, void* d_ws, size_t ws_size,
                              hipStream_t stream) {
    const float* x = (const float*)d_in[0];      // (1, 13, 480, 640) f32
    const int* map = (const int*)d_in[1];        // (1, 307200) i32
    float* out = (float*)d_out;                  // (1, 12, 240, 144, 240) f32

    // Zero the output every call (harness poisons with 0xAA before timing).
    hipMemsetAsync(out, 0, (size_t)NC * VOX_TOTAL_C * sizeof(float), stream);

    const int threads = 256;
    const int blocks = (HW_TOTAL + threads - 1) / threads;
    reproj_scatter_kernel<<<blocks, threads, 0, stream>>>(x, map, out);
}